// Round 8
// baseline (116.748 us; speedup 1.0000x reference)
//
#include <hip/hip_runtime.h>

#pragma clang fp contract(off)

#define B_SZ 16
#define P_SZ 16384
#define C_SZ 80
#define T_SZ 32
#define NCHUNK 32   // match chunks (512 priors each)

typedef float f4 __attribute__((ext_vector_type(4)));

// ws layout (bytes):
// [0, 131072):        u64 keys[16][32][32]
// [131072, 147456):   PartialL pl[1024]
// [147456, 155648):   float pc[2048]
// [155648, +4):       unsigned ticket counter
struct PartialL { float l; float c; unsigned pos; unsigned ign; };

__device__ __forceinline__ float iou_ref(float ax0, float ay0, float ax1, float ay1, float aarea,
                                         float bx0, float by0, float bx1, float by1, float barea) {
    float lx = fmaxf(ax0, bx0), ly = fmaxf(ay0, by0);
    float rx = fminf(ax1, bx1), ry = fminf(ay1, by1);
    float w = fmaxf(rx - lx, 0.0f), h = fmaxf(ry - ly, 0.0f);
    float inter = w * h;
    float denom = (aarea + barea) - inter;
    return inter / denom;
}

// g(x) = sigmoid(x) * softplus(x);  focal(x, t=0) = 0.75*g(x), focal(x, t=1) = 0.25*g(-x)
__device__ __forceinline__ float gfun(float x) {
    float a = fabsf(x);
    float e = __expf(-a);
    float d = 1.0f + e;
    float r = __builtin_amdgcn_rcpf(d);
    float L = __logf(d);
    float sig = (x >= 0.0f) ? r : e * r;   // sigmoid(x)
    float sp  = fmaxf(x, 0.0f) + L;        // softplus(x)
    return sig * sp;
}

// ---------------- K1: per-truth argmax over a 512-prior chunk ----------------
__global__ __launch_bounds__(256) void match_kernel(const float* __restrict__ priors,
                                                    const float* __restrict__ targets,
                                                    unsigned long long* __restrict__ keys,
                                                    unsigned* __restrict__ ticket) {
    const int b = blockIdx.y;
    const int p0 = blockIdx.x * 512;
    const int tid = threadIdx.x;

    if (blockIdx.x == 0 && blockIdx.y == 0 && tid == 0) *ticket = 0;  // reset for this launch

    __shared__ float tx0[T_SZ], ty0[T_SZ], tx1[T_SZ], ty1[T_SZ], tar[T_SZ];
    __shared__ float red_ov[4][T_SZ];
    __shared__ int   red_ix[4][T_SZ];

    if (tid < T_SZ) {
        const float* tp = targets + (b * T_SZ + tid) * 5;
        float x0 = tp[0], y0 = tp[1], x1 = tp[2], y1 = tp[3];
        tx0[tid] = x0; ty0[tid] = y0; tx1[tid] = x1; ty1[tid] = y1;
        tar[tid] = (x1 - x0) * (y1 - y0);
    }
    __syncthreads();

    float bov[T_SZ];
    int   bpi[T_SZ];
#pragma unroll
    for (int t = 0; t < T_SZ; ++t) { bov[t] = -1.0f; bpi[t] = 0x7FFFFFFF; }

#pragma unroll
    for (int i = 0; i < 2; ++i) {
        int p = p0 + tid + i * 256;
        float4 pr = reinterpret_cast<const float4*>(priors)[p];
        float px0 = pr.x - pr.z * 0.5f, py0 = pr.y - pr.w * 0.5f;
        float px1 = pr.x + pr.z * 0.5f, py1 = pr.y + pr.w * 0.5f;
        float parea = (px1 - px0) * (py1 - py0);
#pragma unroll
        for (int t = 0; t < T_SZ; ++t) {
            float iou = iou_ref(tx0[t], ty0[t], tx1[t], ty1[t], tar[t], px0, py0, px1, py1, parea);
            if (iou > bov[t]) { bov[t] = iou; bpi[t] = p; }  // ascending p -> first-index tie-break
        }
    }

    const int lane = tid & 63, wid = tid >> 6;
#pragma unroll
    for (int t = 0; t < T_SZ; ++t) {
        float v = bov[t]; int ix = bpi[t];
#pragma unroll
        for (int off = 32; off > 0; off >>= 1) {
            float v2 = __shfl_down(v, off, 64);
            int   i2 = __shfl_down(ix, off, 64);
            if (v2 > v || (v2 == v && i2 < ix)) { v = v2; ix = i2; }
        }
        if (lane == 0) { red_ov[wid][t] = v; red_ix[wid][t] = ix; }
    }
    __syncthreads();

    if (tid < T_SZ) {
        float v = red_ov[0][tid]; int ix = red_ix[0][tid];
#pragma unroll
        for (int w = 1; w < 4; ++w) {
            float v2 = red_ov[w][tid]; int i2 = red_ix[w][tid];
            if (v2 > v || (v2 == v && i2 < ix)) { v = v2; ix = i2; }
        }
        unsigned long long key = (((unsigned long long)__float_as_uint(v)) << 32)
                               | (unsigned long long)(0xFFFFFFFFu - (unsigned)ix);
        keys[(b * NCHUNK + blockIdx.x) * T_SZ + tid] = key;
    }
}

// ---------------- balanced L1 ----------------
__device__ __forceinline__ float bl1(float pred, float target) {
    const float bC   = (float)19.085536923187668;
    const float aob  = (float)(0.5 / 19.085536923187668);
    const float cL   = (float)(1.5 / 19.085536923187668 - 0.055);
    float d = fabsf(pred - target);
    if (d < 0.11f) {
        return aob * (bC * d + 1.0f) * __logf(bC * d / 0.11f + 1.0f) - 0.5f * d;
    }
    return 1.5f * d + cL;
}

// ---------------- K2: per-prior flag/class + loc loss + focal corrections ----------------
__global__ __launch_bounds__(256) void flags_kernel(const float* __restrict__ loc_data,
                                                    const float* __restrict__ conf_data,
                                                    const float* __restrict__ priors,
                                                    const float* __restrict__ targets,
                                                    const unsigned long long* __restrict__ keys,
                                                    PartialL* __restrict__ pl_out) {
    const int b = blockIdx.y;
    const int p0 = blockIdx.x * 256;
    const int tid = threadIdx.x;
    const int p = p0 + tid;

    __shared__ float tx0[T_SZ], ty0[T_SZ], tx1[T_SZ], ty1[T_SZ], tar[T_SZ];
    __shared__ int tlab[T_SZ], bp[T_SZ];
    __shared__ float rf[4], rc[4];
    __shared__ int rp[4], ri[4];

    if (tid < T_SZ) {
        const float* tp = targets + (b * T_SZ + tid) * 5;
        float x0 = tp[0], y0 = tp[1], x1 = tp[2], y1 = tp[3];
        tx0[tid] = x0; ty0[tid] = y0; tx1[tid] = x1; ty1[tid] = y1;
        tar[tid] = (x1 - x0) * (y1 - y0);
        tlab[tid] = (int)tp[4];
        const unsigned long long* kb = keys + b * (NCHUNK * T_SZ) + tid;
        unsigned long long k = kb[0];
#pragma unroll
        for (int w = 1; w < NCHUNK; ++w) {
            unsigned long long k2 = kb[w * T_SZ];
            if (k2 > k) k = k2;
        }
        bp[tid] = (int)(0xFFFFFFFFu - (unsigned)(k & 0xFFFFFFFFull));
    }
    __syncthreads();

    float4 pr = reinterpret_cast<const float4*>(priors)[p];
    float px0 = pr.x - pr.z * 0.5f, py0 = pr.y - pr.w * 0.5f;
    float px1 = pr.x + pr.z * 0.5f, py1 = pr.y + pr.w * 0.5f;
    float parea = (px1 - px0) * (py1 - py0);

    float ov = -1.0f; int idx = 0;
#pragma unroll
    for (int t = 0; t < T_SZ; ++t) {
        float iou = iou_ref(tx0[t], ty0[t], tx1[t], ty1[t], tar[t], px0, py0, px1, py1, parea);
        if (iou > ov) { ov = iou; idx = t; }
    }
#pragma unroll
    for (int t = 0; t < T_SZ; ++t) if (bp[t] == p) { ov = 2.0f; idx = t; }

    int fl = (ov >= 0.5f) ? 1 : ((ov >= 0.4f) ? 2 : 0);
    int tc = tlab[idx];

    float sum_l = 0.0f, sum_corr = 0.0f;
    int pos_c = 0, ign_c = 0;
    if (fl != 0) {
        // correction for the matched channel: stream added 0.75*g(x); reference wants
        //   fl==1 (pos): 0.25*g(-x)   -> corr = 0.25*g(-x) - 0.75*g(x)
        //   fl==2 (ign): excluded     -> corr = -0.75*g(x)
        float x = conf_data[((size_t)(b * P_SZ + p)) * C_SZ + tc];
        float gx = gfun(x);
        sum_corr = -0.75f * gx;
        if (fl == 1) sum_corr += 0.25f * gfun(-x);
    }
    if (fl == 1) {
        pos_c = 1;
        float4 ld = reinterpret_cast<const float4*>(loc_data)[b * P_SZ + p];
        float mx0 = tx0[idx], my0 = ty0[idx], mx1 = tx1[idx], my1 = ty1[idx];
        float gx = ((mx0 + mx1) * 0.5f - pr.x) / (0.1f * pr.z);
        float gy = ((my0 + my1) * 0.5f - pr.y) / (0.1f * pr.w);
        float gw = __logf((mx1 - mx0) / pr.z) / 0.2f;
        float gh = __logf((my1 - my0) / pr.w) / 0.2f;
        sum_l = bl1(ld.x, gx) + bl1(ld.y, gy) + bl1(ld.z, gw) + bl1(ld.w, gh);
    } else if (fl == 2) {
        ign_c = 1;
    }

    const int lane = tid & 63, wid = tid >> 6;
#pragma unroll
    for (int off = 32; off > 0; off >>= 1) {
        sum_l    += __shfl_down(sum_l, off, 64);
        sum_corr += __shfl_down(sum_corr, off, 64);
        pos_c    += __shfl_down(pos_c, off, 64);
        ign_c    += __shfl_down(ign_c, off, 64);
    }
    if (lane == 0) { rf[wid] = sum_l; rc[wid] = sum_corr; rp[wid] = pos_c; ri[wid] = ign_c; }
    __syncthreads();
    if (tid == 0) {
        PartialL o;
        o.l = rf[0] + rf[1] + rf[2] + rf[3];
        o.c = rc[0] + rc[1] + rc[2] + rc[3];
        o.pos = (unsigned)(rp[0] + rp[1] + rp[2] + rp[3]);
        o.ign = (unsigned)(ri[0] + ri[1] + ri[2] + ri[3]);
        pl_out[b * 64 + blockIdx.x] = o;
    }
}

// ---------------- K3: conf stream, asm-forced 10-deep MLP + ticketed finalize ----------------
__global__ __launch_bounds__(256) void conf_kernel(const float* __restrict__ conf_data,
                                                   const PartialL* __restrict__ pl,
                                                   float* __restrict__ pc_out,
                                                   unsigned* __restrict__ ticket,
                                                   float* __restrict__ out) {
    const int tid = threadIdx.x;
    // uniform SGPR base for this block; per-lane 32-bit byte offsets
    const float* base = conf_data + (size_t)blockIdx.x * 10240;
    unsigned o0 = tid * 16u;

    f4 v0, v1, v2, v3, v4, v5, v6, v7, v8, v9;
    // all 10 loads issued back-to-back (volatile asm preserves mutual order)
    asm volatile("global_load_dwordx4 %0, %1, %2" : "=v"(v0) : "v"(o0),              "s"(base));
    asm volatile("global_load_dwordx4 %0, %1, %2" : "=v"(v1) : "v"(o0 + 1u*4096u),   "s"(base));
    asm volatile("global_load_dwordx4 %0, %1, %2" : "=v"(v2) : "v"(o0 + 2u*4096u),   "s"(base));
    asm volatile("global_load_dwordx4 %0, %1, %2" : "=v"(v3) : "v"(o0 + 3u*4096u),   "s"(base));
    asm volatile("global_load_dwordx4 %0, %1, %2" : "=v"(v4) : "v"(o0 + 4u*4096u),   "s"(base));
    asm volatile("global_load_dwordx4 %0, %1, %2" : "=v"(v5) : "v"(o0 + 5u*4096u),   "s"(base));
    asm volatile("global_load_dwordx4 %0, %1, %2" : "=v"(v6) : "v"(o0 + 6u*4096u),   "s"(base));
    asm volatile("global_load_dwordx4 %0, %1, %2" : "=v"(v7) : "v"(o0 + 7u*4096u),   "s"(base));
    asm volatile("global_load_dwordx4 %0, %1, %2" : "=v"(v8) : "v"(o0 + 8u*4096u),   "s"(base));
    asm volatile("global_load_dwordx4 %0, %1, %2" : "=v"(v9) : "v"(o0 + 9u*4096u),   "s"(base));
    // single drain; ties all results so no consumer can be hoisted above it
    asm volatile("s_waitcnt vmcnt(0)"
                 : "+v"(v0), "+v"(v1), "+v"(v2), "+v"(v3), "+v"(v4),
                   "+v"(v5), "+v"(v6), "+v"(v7), "+v"(v8), "+v"(v9)
                 :: "memory");

    float a0 = 0.0f, a1 = 0.0f, a2 = 0.0f, a3 = 0.0f;
    a0 += gfun(v0[0]); a1 += gfun(v0[1]); a2 += gfun(v0[2]); a3 += gfun(v0[3]);
    a0 += gfun(v1[0]); a1 += gfun(v1[1]); a2 += gfun(v1[2]); a3 += gfun(v1[3]);
    a0 += gfun(v2[0]); a1 += gfun(v2[1]); a2 += gfun(v2[2]); a3 += gfun(v2[3]);
    a0 += gfun(v3[0]); a1 += gfun(v3[1]); a2 += gfun(v3[2]); a3 += gfun(v3[3]);
    a0 += gfun(v4[0]); a1 += gfun(v4[1]); a2 += gfun(v4[2]); a3 += gfun(v4[3]);
    a0 += gfun(v5[0]); a1 += gfun(v5[1]); a2 += gfun(v5[2]); a3 += gfun(v5[3]);
    a0 += gfun(v6[0]); a1 += gfun(v6[1]); a2 += gfun(v6[2]); a3 += gfun(v6[3]);
    a0 += gfun(v7[0]); a1 += gfun(v7[1]); a2 += gfun(v7[2]); a3 += gfun(v7[3]);
    a0 += gfun(v8[0]); a1 += gfun(v8[1]); a2 += gfun(v8[2]); a3 += gfun(v8[3]);
    a0 += gfun(v9[0]); a1 += gfun(v9[1]); a2 += gfun(v9[2]); a3 += gfun(v9[3]);
    float sum_c = (a0 + a1) + (a2 + a3);   // raw g-sum; 0.75 factor applied at finalize

    __shared__ float rf[4];
    const int lane = tid & 63, wid = tid >> 6;
#pragma unroll
    for (int off = 32; off > 0; off >>= 1) sum_c += __shfl_down(sum_c, off, 64);
    if (lane == 0) rf[wid] = sum_c;
    __syncthreads();
    __shared__ bool is_last;
    if (tid == 0) {
        pc_out[blockIdx.x] = rf[0] + rf[1] + rf[2] + rf[3];
        __threadfence();
        unsigned old = atomicAdd(ticket, 1u);
        is_last = (old == 2047u);
    }
    __syncthreads();
    if (!is_last) return;
    __threadfence();  // acquire: all other blocks' pc stores visible

    // ---- finalize (single block, fixed-order reduce) ----
    double sl = 0.0, sc = 0.0;
    unsigned long long np = 0, ni = 0;
#pragma unroll
    for (int k = 0; k < 4; ++k) {
        PartialL q = pl[tid + k * 256];
        sl += (double)q.l; sc += (double)q.c; np += q.pos; ni += q.ign;
    }
    double sg = 0.0;
#pragma unroll
    for (int k = 0; k < 8; ++k) sg += (double)pc_out[tid + k * 256];
    sc += 0.75 * sg;

    __shared__ double r_l[4], r_c[4];
    __shared__ unsigned long long r_p[4], r_i[4];
#pragma unroll
    for (int off = 32; off > 0; off >>= 1) {
        sl += __shfl_down(sl, off, 64);
        sc += __shfl_down(sc, off, 64);
        np += __shfl_down(np, off, 64);
        ni += __shfl_down(ni, off, 64);
    }
    if (lane == 0) { r_l[wid] = sl; r_c[wid] = sc; r_p[wid] = np; r_i[wid] = ni; }
    __syncthreads();
    if (tid == 0) {
        double tl = r_l[0] + r_l[1] + r_l[2] + r_l[3];
        double tc = r_c[0] + r_c[1] + r_c[2] + r_c[3];
        unsigned long long tp = r_p[0] + r_p[1] + r_p[2] + r_p[3];
        long long ti = (long long)(r_i[0] + r_i[1] + r_i[2] + r_i[3]);
        double npos = (tp < 1ull) ? 1.0 : (double)tp;
        long long msum = (long long)B_SZ * P_SZ * C_SZ - ti;
        if (msum < 1) msum = 1;
        out[0] = (float)(tl / (4.0 * npos));
        out[1] = (float)(tc / (double)msum);
    }
}

extern "C" void kernel_launch(void* const* d_in, const int* in_sizes, int n_in,
                              void* d_out, int out_size, void* d_ws, size_t ws_size,
                              hipStream_t stream) {
    const float* loc     = (const float*)d_in[0];
    const float* conf    = (const float*)d_in[1];
    const float* priors  = (const float*)d_in[2];
    const float* targets = (const float*)d_in[3];

    char* ws = (char*)d_ws;
    unsigned long long* keys = (unsigned long long*)ws;          // 131072 B
    PartialL*          plp   = (PartialL*)(ws + 131072);         // 16384 B
    float*             pcp   = (float*)(ws + 147456);            // 8192 B
    unsigned*          tick  = (unsigned*)(ws + 155648);         // 4 B

    match_kernel<<<dim3(NCHUNK, 16), 256, 0, stream>>>(priors, targets, keys, tick);
    flags_kernel<<<dim3(64, 16), 256, 0, stream>>>(loc, conf, priors, targets, keys, plp);
    conf_kernel<<<2048, 256, 0, stream>>>(conf, plp, pcp, tick, (float*)d_out);
}

// Round 9
// 105.768 us; speedup vs baseline: 1.1038x; 1.1038x over previous
//
#include <hip/hip_runtime.h>

#pragma clang fp contract(off)

#define B_SZ 16
#define P_SZ 16384
#define C_SZ 80
#define T_SZ 32
#define NCHUNK 32   // match chunks (512 priors each)

typedef float f4 __attribute__((ext_vector_type(4)));

// ws layout (bytes):
// [0, 131072):        u64 keys[16][32][32]
// [131072, 655360):   ushort codes[16][16384]  (class<<2 | flag)
// [655360, 671744):   PartialL pl[1024]
// [671744, 679936):   float pc[2048]
// [679936, +4):       unsigned ticket counter
struct PartialL { float l; float pad; unsigned pos; unsigned ign; };

__device__ __forceinline__ float iou_ref(float ax0, float ay0, float ax1, float ay1, float aarea,
                                         float bx0, float by0, float bx1, float by1, float barea) {
    float lx = fmaxf(ax0, bx0), ly = fmaxf(ay0, by0);
    float rx = fminf(ax1, bx1), ry = fminf(ay1, by1);
    float w = fmaxf(rx - lx, 0.0f), h = fmaxf(ry - ly, 0.0f);
    float inter = w * h;
    float denom = (aarea + barea) - inter;
    return inter / denom;
}

// g(x) = sigmoid(x) * softplus(x);  focal(x, t=0) = 0.75*g(x), focal(x, t=1) = 0.25*g(-x)
__device__ __forceinline__ float gfun(float x) {
    float a = fabsf(x);
    float e = __expf(-a);
    float d = 1.0f + e;
    float r = __builtin_amdgcn_rcpf(d);
    float L = __logf(d);
    float sig = (x >= 0.0f) ? r : e * r;   // sigmoid(x)
    float sp  = fmaxf(x, 0.0f) + L;        // softplus(x)
    return sig * sp;
}

// ---------------- K1: per-truth argmax over a 512-prior chunk ----------------
__global__ __launch_bounds__(256) void match_kernel(const float* __restrict__ priors,
                                                    const float* __restrict__ targets,
                                                    unsigned long long* __restrict__ keys,
                                                    unsigned* __restrict__ ticket) {
    const int b = blockIdx.y;
    const int p0 = blockIdx.x * 512;
    const int tid = threadIdx.x;

    if (blockIdx.x == 0 && blockIdx.y == 0 && tid == 0) *ticket = 0;  // reset for this launch

    __shared__ float tx0[T_SZ], ty0[T_SZ], tx1[T_SZ], ty1[T_SZ], tar[T_SZ];
    __shared__ float red_ov[4][T_SZ];
    __shared__ int   red_ix[4][T_SZ];

    if (tid < T_SZ) {
        const float* tp = targets + (b * T_SZ + tid) * 5;
        float x0 = tp[0], y0 = tp[1], x1 = tp[2], y1 = tp[3];
        tx0[tid] = x0; ty0[tid] = y0; tx1[tid] = x1; ty1[tid] = y1;
        tar[tid] = (x1 - x0) * (y1 - y0);
    }
    __syncthreads();

    float bov[T_SZ];
    int   bpi[T_SZ];
#pragma unroll
    for (int t = 0; t < T_SZ; ++t) { bov[t] = -1.0f; bpi[t] = 0x7FFFFFFF; }

#pragma unroll
    for (int i = 0; i < 2; ++i) {
        int p = p0 + tid + i * 256;
        float4 pr = reinterpret_cast<const float4*>(priors)[p];
        float px0 = pr.x - pr.z * 0.5f, py0 = pr.y - pr.w * 0.5f;
        float px1 = pr.x + pr.z * 0.5f, py1 = pr.y + pr.w * 0.5f;
        float parea = (px1 - px0) * (py1 - py0);
#pragma unroll
        for (int t = 0; t < T_SZ; ++t) {
            float iou = iou_ref(tx0[t], ty0[t], tx1[t], ty1[t], tar[t], px0, py0, px1, py1, parea);
            if (iou > bov[t]) { bov[t] = iou; bpi[t] = p; }  // ascending p -> first-index tie-break
        }
    }

    const int lane = tid & 63, wid = tid >> 6;
#pragma unroll
    for (int t = 0; t < T_SZ; ++t) {
        float v = bov[t]; int ix = bpi[t];
#pragma unroll
        for (int off = 32; off > 0; off >>= 1) {
            float v2 = __shfl_down(v, off, 64);
            int   i2 = __shfl_down(ix, off, 64);
            if (v2 > v || (v2 == v && i2 < ix)) { v = v2; ix = i2; }
        }
        if (lane == 0) { red_ov[wid][t] = v; red_ix[wid][t] = ix; }
    }
    __syncthreads();

    if (tid < T_SZ) {
        float v = red_ov[0][tid]; int ix = red_ix[0][tid];
#pragma unroll
        for (int w = 1; w < 4; ++w) {
            float v2 = red_ov[w][tid]; int i2 = red_ix[w][tid];
            if (v2 > v || (v2 == v && i2 < ix)) { v = v2; ix = i2; }
        }
        unsigned long long key = (((unsigned long long)__float_as_uint(v)) << 32)
                               | (unsigned long long)(0xFFFFFFFFu - (unsigned)ix);
        keys[(b * NCHUNK + blockIdx.x) * T_SZ + tid] = key;
    }
}

// ---------------- balanced L1 ----------------
__device__ __forceinline__ float bl1(float pred, float target) {
    const float bC   = (float)19.085536923187668;
    const float aob  = (float)(0.5 / 19.085536923187668);
    const float cL   = (float)(1.5 / 19.085536923187668 - 0.055);
    float d = fabsf(pred - target);
    if (d < 0.11f) {
        return aob * (bC * d + 1.0f) * __logf(bC * d / 0.11f + 1.0f) - 0.5f * d;
    }
    return 1.5f * d + cL;
}

// ---------------- K2: per-prior flag/class codes + loc loss ----------------
__global__ __launch_bounds__(256) void flags_kernel(const float* __restrict__ loc_data,
                                                    const float* __restrict__ priors,
                                                    const float* __restrict__ targets,
                                                    const unsigned long long* __restrict__ keys,
                                                    unsigned short* __restrict__ codes,
                                                    PartialL* __restrict__ pl_out) {
    const int b = blockIdx.y;
    const int p0 = blockIdx.x * 256;
    const int tid = threadIdx.x;
    const int p = p0 + tid;

    __shared__ float tx0[T_SZ], ty0[T_SZ], tx1[T_SZ], ty1[T_SZ], tar[T_SZ];
    __shared__ int tlab[T_SZ], bp[T_SZ];
    __shared__ float rf[4];
    __shared__ int rp[4], ri[4];

    if (tid < T_SZ) {
        const float* tp = targets + (b * T_SZ + tid) * 5;
        float x0 = tp[0], y0 = tp[1], x1 = tp[2], y1 = tp[3];
        tx0[tid] = x0; ty0[tid] = y0; tx1[tid] = x1; ty1[tid] = y1;
        tar[tid] = (x1 - x0) * (y1 - y0);
        tlab[tid] = (int)tp[4];
        const unsigned long long* kb = keys + b * (NCHUNK * T_SZ) + tid;
        unsigned long long k = kb[0];
#pragma unroll
        for (int w = 1; w < NCHUNK; ++w) {
            unsigned long long k2 = kb[w * T_SZ];
            if (k2 > k) k = k2;
        }
        bp[tid] = (int)(0xFFFFFFFFu - (unsigned)(k & 0xFFFFFFFFull));
    }
    __syncthreads();

    float4 pr = reinterpret_cast<const float4*>(priors)[p];
    float px0 = pr.x - pr.z * 0.5f, py0 = pr.y - pr.w * 0.5f;
    float px1 = pr.x + pr.z * 0.5f, py1 = pr.y + pr.w * 0.5f;
    float parea = (px1 - px0) * (py1 - py0);

    float ov = -1.0f; int idx = 0;
#pragma unroll
    for (int t = 0; t < T_SZ; ++t) {
        float iou = iou_ref(tx0[t], ty0[t], tx1[t], ty1[t], tar[t], px0, py0, px1, py1, parea);
        if (iou > ov) { ov = iou; idx = t; }
    }
#pragma unroll
    for (int t = 0; t < T_SZ; ++t) if (bp[t] == p) { ov = 2.0f; idx = t; }

    int fl = (ov >= 0.5f) ? 1 : ((ov >= 0.4f) ? 2 : 0);
    int tc = tlab[idx];
    codes[b * P_SZ + p] = (unsigned short)((tc << 2) | fl);

    float sum_l = 0.0f;
    int pos_c = 0, ign_c = 0;
    if (fl == 1) {
        pos_c = 1;
        float4 ld = reinterpret_cast<const float4*>(loc_data)[b * P_SZ + p];
        float mx0 = tx0[idx], my0 = ty0[idx], mx1 = tx1[idx], my1 = ty1[idx];
        float gx = ((mx0 + mx1) * 0.5f - pr.x) / (0.1f * pr.z);
        float gy = ((my0 + my1) * 0.5f - pr.y) / (0.1f * pr.w);
        float gw = __logf((mx1 - mx0) / pr.z) / 0.2f;
        float gh = __logf((my1 - my0) / pr.w) / 0.2f;
        sum_l = bl1(ld.x, gx) + bl1(ld.y, gy) + bl1(ld.z, gw) + bl1(ld.w, gh);
    } else if (fl == 2) {
        ign_c = 1;
    }

    const int lane = tid & 63, wid = tid >> 6;
#pragma unroll
    for (int off = 32; off > 0; off >>= 1) {
        sum_l += __shfl_down(sum_l, off, 64);
        pos_c += __shfl_down(pos_c, off, 64);
        ign_c += __shfl_down(ign_c, off, 64);
    }
    if (lane == 0) { rf[wid] = sum_l; rp[wid] = pos_c; ri[wid] = ign_c; }
    __syncthreads();
    if (tid == 0) {
        PartialL o;
        o.l = rf[0] + rf[1] + rf[2] + rf[3];
        o.pad = 0.0f;
        o.pos = (unsigned)(rp[0] + rp[1] + rp[2] + rp[3]);
        o.ign = (unsigned)(ri[0] + ri[1] + ri[2] + ri[3]);
        pl_out[b * 64 + blockIdx.x] = o;
    }
}

// ---------------- K3: LDS-staged conf stream + corrections + ticketed finalize ----------------
__global__ __launch_bounds__(256) void conf_kernel(const float* __restrict__ conf_data,
                                                   const unsigned short* __restrict__ codes,
                                                   const PartialL* __restrict__ pl,
                                                   float* __restrict__ pc_out,
                                                   unsigned* __restrict__ ticket,
                                                   float* __restrict__ out) {
    __shared__ float smem[10240];   // exactly 40960 B -> 4 blocks/CU
    const int tid = threadIdx.x;
    const int lane = tid & 63, wid = tid >> 6;

    // early code load (latency hides under staging)
    unsigned short cdv = 0;
    if (tid < 128) cdv = codes[blockIdx.x * 128 + tid];

    // stage 40 KB via global_load_lds: MLP lives in the vmcnt queue, zero VGPR cost
    const char* gbase = (const char*)conf_data + (size_t)blockIdx.x * 40960;
#pragma unroll
    for (int i = 0; i < 10; ++i) {
        const void* g = gbase + i * 4096 + wid * 1024 + lane * 16;
        void* l = (char*)smem + i * 4096 + wid * 1024;   // wave-uniform base; HW adds lane*16
        __builtin_amdgcn_global_load_lds((const __attribute__((address_space(1))) unsigned*)g,
                                         (__attribute__((address_space(3))) unsigned*)l,
                                         16, 0, 0);
    }
    asm volatile("s_waitcnt vmcnt(0)" ::: "memory");
    __syncthreads();

    // compute: 10 x (ds_read_b128 + 4 gfun)
    float a0 = 0.0f, a1 = 0.0f, a2 = 0.0f, a3 = 0.0f;
    const f4* sm = (const f4*)smem;
#pragma unroll
    for (int i = 0; i < 10; ++i) {
        f4 v = sm[tid + i * 256];
        a0 += gfun(v[0]); a1 += gfun(v[1]); a2 += gfun(v[2]); a3 += gfun(v[3]);
    }

    // corrections for this block's 128 priors, from staged LDS data
    float corr = 0.0f;
    if (tid < 128) {
        int fl = cdv & 3;
        if (fl) {
            int tc = cdv >> 2;
            float x = smem[tid * 80 + tc];
            corr = -0.75f * gfun(x);
            if (fl == 1) corr += 0.25f * gfun(-x);
        }
    }

    float total = 0.75f * ((a0 + a1) + (a2 + a3)) + corr;
#pragma unroll
    for (int off = 32; off > 0; off >>= 1) total += __shfl_down(total, off, 64);

    __syncthreads();                       // all smem reads done before reuse as scratch
    float* smemf = smem;
    int*   smi   = (int*)smem;
    if (lane == 0) smemf[wid] = total;
    __syncthreads();
    if (tid == 0) {
        pc_out[blockIdx.x] = smemf[0] + smemf[1] + smemf[2] + smemf[3];
        __threadfence();
        unsigned old = atomicAdd(ticket, 1u);
        smi[4] = (old == 2047u) ? 1 : 0;
    }
    __syncthreads();
    if (smi[4] == 0) return;
    __threadfence();  // acquire: all other blocks' pc stores visible

    // ---- finalize (single block, fixed-order reduce) ----
    double sl = 0.0, sc = 0.0;
    unsigned long long np = 0, ni = 0;
#pragma unroll
    for (int k = 0; k < 4; ++k) {
        PartialL q = pl[tid + k * 256];
        sl += (double)q.l; np += q.pos; ni += q.ign;
    }
#pragma unroll
    for (int k = 0; k < 8; ++k) sc += (double)pc_out[tid + k * 256];

#pragma unroll
    for (int off = 32; off > 0; off >>= 1) {
        sl += __shfl_down(sl, off, 64);
        sc += __shfl_down(sc, off, 64);
        np += __shfl_down(np, off, 64);
        ni += __shfl_down(ni, off, 64);
    }
    __syncthreads();
    double* dsc = (double*)smem;                      // [0..7] doubles
    unsigned long long* usc = (unsigned long long*)smem;  // [8..15]
    if (lane == 0) { dsc[wid] = sl; dsc[4 + wid] = sc; usc[8 + wid] = np; usc[12 + wid] = ni; }
    __syncthreads();
    if (tid == 0) {
        double tl = dsc[0] + dsc[1] + dsc[2] + dsc[3];
        double tc = dsc[4] + dsc[5] + dsc[6] + dsc[7];
        unsigned long long tp = usc[8] + usc[9] + usc[10] + usc[11];
        long long ti = (long long)(usc[12] + usc[13] + usc[14] + usc[15]);
        double npos = (tp < 1ull) ? 1.0 : (double)tp;
        long long msum = (long long)B_SZ * P_SZ * C_SZ - ti;
        if (msum < 1) msum = 1;
        out[0] = (float)(tl / (4.0 * npos));
        out[1] = (float)(tc / (double)msum);
    }
}

extern "C" void kernel_launch(void* const* d_in, const int* in_sizes, int n_in,
                              void* d_out, int out_size, void* d_ws, size_t ws_size,
                              hipStream_t stream) {
    const float* loc     = (const float*)d_in[0];
    const float* conf    = (const float*)d_in[1];
    const float* priors  = (const float*)d_in[2];
    const float* targets = (const float*)d_in[3];

    char* ws = (char*)d_ws;
    unsigned long long* keys = (unsigned long long*)ws;          // 131072 B
    unsigned short*    codes = (unsigned short*)(ws + 131072);   // 524288 B
    PartialL*          plp   = (PartialL*)(ws + 655360);         // 16384 B
    float*             pcp   = (float*)(ws + 671744);            // 8192 B
    unsigned*          tick  = (unsigned*)(ws + 679936);         // 4 B

    match_kernel<<<dim3(NCHUNK, 16), 256, 0, stream>>>(priors, targets, keys, tick);
    flags_kernel<<<dim3(64, 16), 256, 0, stream>>>(loc, priors, targets, keys, codes, plp);
    conf_kernel<<<2048, 256, 0, stream>>>(conf, codes, plp, pcp, tick, (float*)d_out);
}

// Round 10
// 66.252 us; speedup vs baseline: 1.7622x; 1.5965x over previous
//
#include <hip/hip_runtime.h>

#pragma clang fp contract(off)

#define B_SZ 16
#define P_SZ 16384
#define C_SZ 80
#define T_SZ 32
#define NCHUNK 32   // match chunks (512 priors each)

typedef float f4 __attribute__((ext_vector_type(4)));

// ws layout (bytes):
// [0, 131072):        u64 keys[16][32][32]
// [131072, 655360):   ushort codes[16][16384]  (class<<2 | flag)
// [655360, 671744):   PartialL pl[1024]
// [671744, 675840):   float pc[1024]
struct PartialL { float l; float pad; unsigned pos; unsigned ign; };

__device__ __forceinline__ float iou_ref(float ax0, float ay0, float ax1, float ay1, float aarea,
                                         float bx0, float by0, float bx1, float by1, float barea) {
    float lx = fmaxf(ax0, bx0), ly = fmaxf(ay0, by0);
    float rx = fminf(ax1, bx1), ry = fminf(ay1, by1);
    float w = fmaxf(rx - lx, 0.0f), h = fmaxf(ry - ly, 0.0f);
    float inter = w * h;
    float denom = (aarea + barea) - inter;
    return inter / denom;
}

// g(x) = sigmoid(x) * softplus(x);  focal(x, t=0) = 0.75*g(x), focal(x, t=1) = 0.25*g(-x)
__device__ __forceinline__ float gfun(float x) {
    float a = fabsf(x);
    float e = __expf(-a);
    float d = 1.0f + e;
    float r = __builtin_amdgcn_rcpf(d);
    float L = __logf(d);
    float sig = (x >= 0.0f) ? r : e * r;   // sigmoid(x)
    float sp  = fmaxf(x, 0.0f) + L;        // softplus(x)
    return sig * sp;
}

// ---------------- K1: per-truth argmax over a 512-prior chunk ----------------
__global__ __launch_bounds__(256) void match_kernel(const float* __restrict__ priors,
                                                    const float* __restrict__ targets,
                                                    unsigned long long* __restrict__ keys) {
    const int b = blockIdx.y;
    const int p0 = blockIdx.x * 512;
    const int tid = threadIdx.x;

    __shared__ float tx0[T_SZ], ty0[T_SZ], tx1[T_SZ], ty1[T_SZ], tar[T_SZ];
    __shared__ float red_ov[4][T_SZ];
    __shared__ int   red_ix[4][T_SZ];

    if (tid < T_SZ) {
        const float* tp = targets + (b * T_SZ + tid) * 5;
        float x0 = tp[0], y0 = tp[1], x1 = tp[2], y1 = tp[3];
        tx0[tid] = x0; ty0[tid] = y0; tx1[tid] = x1; ty1[tid] = y1;
        tar[tid] = (x1 - x0) * (y1 - y0);
    }
    __syncthreads();

    float bov[T_SZ];
    int   bpi[T_SZ];
#pragma unroll
    for (int t = 0; t < T_SZ; ++t) { bov[t] = -1.0f; bpi[t] = 0x7FFFFFFF; }

#pragma unroll
    for (int i = 0; i < 2; ++i) {
        int p = p0 + tid + i * 256;
        float4 pr = reinterpret_cast<const float4*>(priors)[p];
        float px0 = pr.x - pr.z * 0.5f, py0 = pr.y - pr.w * 0.5f;
        float px1 = pr.x + pr.z * 0.5f, py1 = pr.y + pr.w * 0.5f;
        float parea = (px1 - px0) * (py1 - py0);
#pragma unroll
        for (int t = 0; t < T_SZ; ++t) {
            float iou = iou_ref(tx0[t], ty0[t], tx1[t], ty1[t], tar[t], px0, py0, px1, py1, parea);
            if (iou > bov[t]) { bov[t] = iou; bpi[t] = p; }  // ascending p -> first-index tie-break
        }
    }

    const int lane = tid & 63, wid = tid >> 6;
#pragma unroll
    for (int t = 0; t < T_SZ; ++t) {
        float v = bov[t]; int ix = bpi[t];
#pragma unroll
        for (int off = 32; off > 0; off >>= 1) {
            float v2 = __shfl_down(v, off, 64);
            int   i2 = __shfl_down(ix, off, 64);
            if (v2 > v || (v2 == v && i2 < ix)) { v = v2; ix = i2; }
        }
        if (lane == 0) { red_ov[wid][t] = v; red_ix[wid][t] = ix; }
    }
    __syncthreads();

    if (tid < T_SZ) {
        float v = red_ov[0][tid]; int ix = red_ix[0][tid];
#pragma unroll
        for (int w = 1; w < 4; ++w) {
            float v2 = red_ov[w][tid]; int i2 = red_ix[w][tid];
            if (v2 > v || (v2 == v && i2 < ix)) { v = v2; ix = i2; }
        }
        unsigned long long key = (((unsigned long long)__float_as_uint(v)) << 32)
                               | (unsigned long long)(0xFFFFFFFFu - (unsigned)ix);
        keys[(b * NCHUNK + blockIdx.x) * T_SZ + tid] = key;
    }
}

// ---------------- balanced L1 ----------------
__device__ __forceinline__ float bl1(float pred, float target) {
    const float bC   = (float)19.085536923187668;
    const float aob  = (float)(0.5 / 19.085536923187668);
    const float cL   = (float)(1.5 / 19.085536923187668 - 0.055);
    float d = fabsf(pred - target);
    if (d < 0.11f) {
        return aob * (bC * d + 1.0f) * __logf(bC * d / 0.11f + 1.0f) - 0.5f * d;
    }
    return 1.5f * d + cL;
}

// ---------------- K2: per-prior flag/class codes + loc loss ----------------
__global__ __launch_bounds__(256) void flags_kernel(const float* __restrict__ loc_data,
                                                    const float* __restrict__ priors,
                                                    const float* __restrict__ targets,
                                                    const unsigned long long* __restrict__ keys,
                                                    unsigned short* __restrict__ codes,
                                                    PartialL* __restrict__ pl_out) {
    const int b = blockIdx.y;
    const int p0 = blockIdx.x * 256;
    const int tid = threadIdx.x;
    const int p = p0 + tid;

    __shared__ float tx0[T_SZ], ty0[T_SZ], tx1[T_SZ], ty1[T_SZ], tar[T_SZ];
    __shared__ int tlab[T_SZ], bp[T_SZ];
    __shared__ float rf[4];
    __shared__ int rp[4], ri[4];

    if (tid < T_SZ) {
        const float* tp = targets + (b * T_SZ + tid) * 5;
        float x0 = tp[0], y0 = tp[1], x1 = tp[2], y1 = tp[3];
        tx0[tid] = x0; ty0[tid] = y0; tx1[tid] = x1; ty1[tid] = y1;
        tar[tid] = (x1 - x0) * (y1 - y0);
        tlab[tid] = (int)tp[4];
        const unsigned long long* kb = keys + b * (NCHUNK * T_SZ) + tid;
        unsigned long long k = kb[0];
#pragma unroll
        for (int w = 1; w < NCHUNK; ++w) {
            unsigned long long k2 = kb[w * T_SZ];
            if (k2 > k) k = k2;
        }
        bp[tid] = (int)(0xFFFFFFFFu - (unsigned)(k & 0xFFFFFFFFull));
    }
    __syncthreads();

    float4 pr = reinterpret_cast<const float4*>(priors)[p];
    float px0 = pr.x - pr.z * 0.5f, py0 = pr.y - pr.w * 0.5f;
    float px1 = pr.x + pr.z * 0.5f, py1 = pr.y + pr.w * 0.5f;
    float parea = (px1 - px0) * (py1 - py0);

    float ov = -1.0f; int idx = 0;
#pragma unroll
    for (int t = 0; t < T_SZ; ++t) {
        float iou = iou_ref(tx0[t], ty0[t], tx1[t], ty1[t], tar[t], px0, py0, px1, py1, parea);
        if (iou > ov) { ov = iou; idx = t; }
    }
#pragma unroll
    for (int t = 0; t < T_SZ; ++t) if (bp[t] == p) { ov = 2.0f; idx = t; }

    int fl = (ov >= 0.5f) ? 1 : ((ov >= 0.4f) ? 2 : 0);
    int tc = tlab[idx];
    codes[b * P_SZ + p] = (unsigned short)((tc << 2) | fl);

    float sum_l = 0.0f;
    int pos_c = 0, ign_c = 0;
    if (fl == 1) {
        pos_c = 1;
        float4 ld = reinterpret_cast<const float4*>(loc_data)[b * P_SZ + p];
        float mx0 = tx0[idx], my0 = ty0[idx], mx1 = tx1[idx], my1 = ty1[idx];
        float gx = ((mx0 + mx1) * 0.5f - pr.x) / (0.1f * pr.z);
        float gy = ((my0 + my1) * 0.5f - pr.y) / (0.1f * pr.w);
        float gw = __logf((mx1 - mx0) / pr.z) / 0.2f;
        float gh = __logf((my1 - my0) / pr.w) / 0.2f;
        sum_l = bl1(ld.x, gx) + bl1(ld.y, gy) + bl1(ld.z, gw) + bl1(ld.w, gh);
    } else if (fl == 2) {
        ign_c = 1;
    }

    const int lane = tid & 63, wid = tid >> 6;
#pragma unroll
    for (int off = 32; off > 0; off >>= 1) {
        sum_l += __shfl_down(sum_l, off, 64);
        pos_c += __shfl_down(pos_c, off, 64);
        ign_c += __shfl_down(ign_c, off, 64);
    }
    if (lane == 0) { rf[wid] = sum_l; rp[wid] = pos_c; ri[wid] = ign_c; }
    __syncthreads();
    if (tid == 0) {
        PartialL o;
        o.l = rf[0] + rf[1] + rf[2] + rf[3];
        o.pad = 0.0f;
        o.pos = (unsigned)(rp[0] + rp[1] + rp[2] + rp[3]);
        o.ign = (unsigned)(ri[0] + ri[1] + ri[2] + ri[3]);
        pl_out[b * 64 + blockIdx.x] = o;
    }
}

// ---------------- K3: persistent double-buffered conf stream ----------------
// 1024 blocks (4/CU, all resident). Each block: 4 tiles x 20KB, 2-phase dbuf,
// counted vmcnt (never 0 mid-loop), raw s_barrier (no implicit vmcnt drain).
__device__ __forceinline__ void stage_tile(const char* gtile, char* lbuf, int wid, int lane) {
#pragma unroll
    for (int i = 0; i < 5; ++i) {
        const char* g = gtile + (wid * 5 + i) * 1024 + lane * 16;
        char* l = lbuf + (wid * 5 + i) * 1024;   // wave-uniform base; HW adds lane*16
        __builtin_amdgcn_global_load_lds((const __attribute__((address_space(1))) unsigned*)g,
                                         (__attribute__((address_space(3))) unsigned*)l,
                                         16, 0, 0);
    }
}

__global__ __launch_bounds__(256) void conf_kernel(const float* __restrict__ conf_data,
                                                   const unsigned short* __restrict__ codes,
                                                   float* __restrict__ pc_out) {
    __shared__ f4 buf[2][1280];   // 2 x 20480 B = 40960 B -> 4 blocks/CU
    const int tid = threadIdx.x;
    const int lane = tid & 63, wid = tid >> 6;
    const int blk = blockIdx.x;

    // code for this thread's prior (prior q = blk*256 + tid); consumed in tile t = tid>>6
    unsigned short cdv = codes[blk * 256 + tid];

    const char* gbase = (const char*)conf_data + (size_t)blk * 81920;   // 4 tiles

    float a0 = 0.0f, a1 = 0.0f, a2 = 0.0f, a3 = 0.0f, corr = 0.0f;

    stage_tile(gbase, (char*)&buf[0][0], wid, lane);
#pragma unroll
    for (int t = 0; t < 4; ++t) {
        const int cur = t & 1;
        if (t < 3) {
            stage_tile(gbase + (t + 1) * 20480, (char*)&buf[cur ^ 1][0], wid, lane);
            asm volatile("s_waitcnt vmcnt(5)" ::: "memory");   // cur tile done, next 5 in flight
        } else {
            asm volatile("s_waitcnt vmcnt(0)" ::: "memory");
        }
        __builtin_amdgcn_s_barrier();
        __builtin_amdgcn_sched_barrier(0);

        const f4* bp = &buf[cur][0];
#pragma unroll
        for (int j = 0; j < 5; ++j) {
            f4 v = bp[tid + j * 256];
            a0 += gfun(v[0]); a1 += gfun(v[1]); a2 += gfun(v[2]); a3 += gfun(v[3]);
        }
        // corrections: wave t handles this tile's 64 priors
        if (wid == t) {
            int fl = cdv & 3;
            if (fl) {
                int tc = cdv >> 2;
                float x = ((const float*)bp)[(tid & 63) * 80 + tc];
                corr += -0.75f * gfun(x);
                if (fl == 1) corr += 0.25f * gfun(-x);
            }
        }
        __builtin_amdgcn_sched_barrier(0);
        __builtin_amdgcn_s_barrier();     // reads done before this buf is re-staged
    }

    float total = 0.75f * ((a0 + a1) + (a2 + a3)) + corr;
#pragma unroll
    for (int off = 32; off > 0; off >>= 1) total += __shfl_down(total, off, 64);

    float* scr = (float*)&buf[0][0];      // safe: last compute used buf[1]
    if (lane == 0) scr[wid] = total;
    __syncthreads();
    if (tid == 0) pc_out[blk] = scr[0] + scr[1] + scr[2] + scr[3];
}

// ---------------- K4: finalize ----------------
__global__ __launch_bounds__(256) void finalize_kernel(const PartialL* __restrict__ pl,
                                                       const float* __restrict__ pc,
                                                       float* __restrict__ out) {
    const int tid = threadIdx.x;
    __shared__ double r_l[4], r_c[4];
    __shared__ unsigned long long r_p[4], r_i[4];

    double sl = 0.0, sc = 0.0;
    unsigned long long np = 0, ni = 0;
#pragma unroll
    for (int k = 0; k < 4; ++k) {
        PartialL q = pl[tid + k * 256];
        sl += (double)q.l; np += q.pos; ni += q.ign;
        sc += (double)pc[tid + k * 256];
    }
    const int lane = tid & 63, wid = tid >> 6;
#pragma unroll
    for (int off = 32; off > 0; off >>= 1) {
        sl += __shfl_down(sl, off, 64);
        sc += __shfl_down(sc, off, 64);
        np += __shfl_down(np, off, 64);
        ni += __shfl_down(ni, off, 64);
    }
    if (lane == 0) { r_l[wid] = sl; r_c[wid] = sc; r_p[wid] = np; r_i[wid] = ni; }
    __syncthreads();
    if (tid == 0) {
        double tl = r_l[0] + r_l[1] + r_l[2] + r_l[3];
        double tc = r_c[0] + r_c[1] + r_c[2] + r_c[3];
        unsigned long long tp = r_p[0] + r_p[1] + r_p[2] + r_p[3];
        long long ti = (long long)(r_i[0] + r_i[1] + r_i[2] + r_i[3]);
        double npos = (tp < 1ull) ? 1.0 : (double)tp;
        long long msum = (long long)B_SZ * P_SZ * C_SZ - ti;
        if (msum < 1) msum = 1;
        out[0] = (float)(tl / (4.0 * npos));
        out[1] = (float)(tc / (double)msum);
    }
}

extern "C" void kernel_launch(void* const* d_in, const int* in_sizes, int n_in,
                              void* d_out, int out_size, void* d_ws, size_t ws_size,
                              hipStream_t stream) {
    const float* loc     = (const float*)d_in[0];
    const float* conf    = (const float*)d_in[1];
    const float* priors  = (const float*)d_in[2];
    const float* targets = (const float*)d_in[3];

    char* ws = (char*)d_ws;
    unsigned long long* keys = (unsigned long long*)ws;          // 131072 B
    unsigned short*    codes = (unsigned short*)(ws + 131072);   // 524288 B
    PartialL*          plp   = (PartialL*)(ws + 655360);         // 16384 B
    float*             pcp   = (float*)(ws + 671744);            // 4096 B

    match_kernel<<<dim3(NCHUNK, 16), 256, 0, stream>>>(priors, targets, keys);
    flags_kernel<<<dim3(64, 16), 256, 0, stream>>>(loc, priors, targets, keys, codes, plp);
    conf_kernel<<<1024, 256, 0, stream>>>(conf, codes, pcp);
    finalize_kernel<<<1, 256, 0, stream>>>(plp, pcp, (float*)d_out);
}